// Round 1
// baseline (183.057 us; speedup 1.0000x reference)
//
#include <hip/hip_runtime.h>

namespace {
constexpr int S = 1024;
constexpr int B = 32;
constexpr int OFF = 256; // (S-H)/2 = (S-W)/2

typedef float f32x4 __attribute__((ext_vector_type(4)));

// stripe indicator as float {0,1}; exact int div by runtime gb via float
// reciprocal estimate + one-step fixup (|err| < 1 for d <= 1024, gb >= 153)
__device__ __forceinline__ float stripef(int i, int start, int gb, int len, int n, float inv_gb) {
    const int d = i - start;
    int q = (int)((float)d * inv_gb);
    int r = d - q * gb;
    if (r < 0)        { r += gb; --q; }
    else if (r >= gb) { r -= gb; ++q; }
    return (d >= 0 && r < len && q < n) ? 1.0f : 0.0f;
}

__global__ __launch_bounds__(512) void gridmask_kernel(
    const float* __restrict__ images,
    const float* __restrict__ angles,
    const int* __restrict__ gridblock,
    const int* __restrict__ start1,
    const int* __restrict__ start2,
    float* __restrict__ out)
{
    // 1D separable LUTs: {value[i], value[i+1]-value[i]} per entry.
    __shared__ float2 colsAD[1024];   // 8 KB
    __shared__ float2 rowsAD[1024];   // 8 KB
    __shared__ float  mlds[4096];     // 16 KB  (8 rows x 512 cols tile)

    const int tid = threadIdx.x;        // 0..511
    const int blk = blockIdx.x;         // 2048 blocks
    const int b   = blk >> 6;           // 64 blocks per image
    const int y0  = (blk & 63) << 3;    // tile top row [0,512), 8 rows per tile

    // ---- issue all phase-2 global loads up front: HBM latency hides under
    // the LUT build + mask compute (no LDS dependence) ----
    const size_t fbase = (size_t)blk * 12288;   // 4096 px * 3 ch
    const float4* __restrict__ gin4 = (const float4*)(images + fbase);
    float4 p[6];
#pragma unroll
    for (int j = 0; j < 6; ++j) p[j] = gin4[(j << 9) + tid];

    const float ang = angles[b];
    const int gb = gridblock[b];
    const int s1 = start1[b];
    const int s2 = start2[b];

    const float gbf = (float)gb;
    // match numpy's two-step f32 rounding exactly: no FMA contraction
    int len = (int)(__fadd_rn(__fmul_rn(gbf, 0.6f), 0.5f));
    len = min(max(len, 1), gb - 1);
    const int n = S / gb;
    const float inv_gb = 1.0f / gbf;

    // ---- LUT build: thread t fills entries 2t, 2t+1 of both tables ----
    {
        const int i0 = tid << 1;
        const float r0 = stripef(i0,     s1, gb, len, n, inv_gb);
        const float r1 = stripef(i0 + 1, s1, gb, len, n, inv_gb);
        const float r2 = stripef(i0 + 2, s1, gb, len, n, inv_gb);
        rowsAD[i0]     = make_float2(r0, r1 - r0);
        rowsAD[i0 + 1] = make_float2(r1, r2 - r1);
        const float c0 = stripef(i0,     s2, gb, len, n, inv_gb);
        const float c1 = stripef(i0 + 1, s2, gb, len, n, inv_gb);
        const float c2 = stripef(i0 + 2, s2, gb, len, n, inv_gb);
        colsAD[i0]     = make_float2(c0, c1 - c0);
        colsAD[i0 + 1] = make_float2(c1, c2 - c1);
    }
    __syncthreads();

    // ---- phase 1: mask for this thread's column x=tid, 8 consecutive rows.
    // Separable closed form of the 4-tap bilinear of (rows|cols):
    //   m = ry + cx - ry*cx,  ry = r0 + fy*(r1-r0),  cx = c0 + fx*(c1-c0)
    // Reflection is provably the identity here: sx,sy in [154.5, 868.5]
    // for |angle| <= 0.2*2pi and the centered HxW crop, so no refl/clamp.
    {
        float sn, cs;
        sincosf(ang, &sn, &cs);
        const float c = (float)(S - 1) * 0.5f;   // 511.5
        const float X = (float)(tid + OFF) - c;
#pragma unroll
        for (int r = 0; r < 8; ++r) {
            const float Yr = (float)(y0 + r + OFF) - c;
            const float sx = cs * X + sn * Yr + c;
            const float sy = cs * Yr - sn * X + c;
            const float x0f = floorf(sx);
            const float y0f = floorf(sy);
            const float fx = sx - x0f;
            const float fy = sy - y0f;
            const int xi = (int)x0f;             // in [154, 868]
            const int yi = (int)y0f;
            const float2 cad = colsAD[xi];       // ds_read_b64, ~consecutive across lanes
            const float2 rad = rowsAD[yi];       // ds_read_b64, ~broadcast across lanes
            const float cx = fmaf(fx, cad.y, cad.x);
            const float ry = fmaf(fy, rad.y, rad.x);
            mlds[(r << 9) + tid] = cx + ry - cx * ry;
        }
    }
    __syncthreads();

    // ---- phase 2: fully coalesced multiply sweep, nontemporal stores ----
    f32x4* __restrict__ gout4 = (f32x4*)(out + fbase);
#pragma unroll
    for (int j = 0; j < 6; ++j) {
        const int lf = (j << 11) + (tid << 2);   // local float index [0,12288)
        const int q  = lf / 3;                   // pixel of first component
        const int r  = lf - q * 3;
        const float ma = mlds[q];
        const float mb = mlds[min(q + 1, 4095)];
        // component c belongs to pixel q + ((r+c) >= 3)
        const float m0 = ma;
        const float m1 = (r + 1 >= 3) ? mb : ma;
        const float m2 = (r + 2 >= 3) ? mb : ma;
        const float m3 = (r + 3 >= 3) ? mb : ma;
        f32x4 o;
        o.x = p[j].x * m0;
        o.y = p[j].y * m1;
        o.z = p[j].z * m2;
        o.w = p[j].w * m3;
        __builtin_nontemporal_store(o, gout4 + (j << 9) + tid);
    }
}
} // namespace

extern "C" void kernel_launch(void* const* d_in, const int* in_sizes, int n_in,
                              void* d_out, int out_size, void* d_ws, size_t ws_size,
                              hipStream_t stream) {
    const float* images    = (const float*)d_in[0];
    const float* angles    = (const float*)d_in[1];
    const int*   gridblock = (const int*)d_in[2];
    const int*   start1    = (const int*)d_in[3];
    const int*   start2    = (const int*)d_in[4];
    float* outp = (float*)d_out;

    // 2048 blocks x 512 threads; each block: 8 rows x 512 cols = 4096 px
    gridmask_kernel<<<2048, 512, 0, stream>>>(images, angles, gridblock, start1, start2, outp);
}